// Round 1
// baseline (17606.801 us; speedup 1.0000x reference)
//
#include <hip/hip_runtime.h>
#include <hip/hip_bf16.h>
#include <hip/hip_cooperative_groups.h>

namespace cg = cooperative_groups;

// Problem dims
#define BB 32
#define SS 128
#define TT 64
#define EE 64
#define HH 512
#define H3 1536
#define VV 32000
#define EHD 576      // E + H (dec0 input width)
#define TD 63        // decoder steps
#define MFC 2048     // padded M for fc GEMM (63*32 = 2016 real rows)

typedef unsigned short u16;
typedef unsigned int   u32;

typedef __attribute__((ext_vector_type(8))) short bf16x8;
typedef __attribute__((ext_vector_type(4))) float f32x4;

__device__ __forceinline__ float bf2f(u16 u){ return __uint_as_float(((u32)u)<<16); }
__device__ __forceinline__ u16 f2bf(float f){
  u32 u = __float_as_uint(f);
  u += 0x7FFFu + ((u>>16)&1u);       // RNE
  return (u16)(u>>16);
}
__device__ __forceinline__ float sigm(float x){ return 1.f/(1.f+__expf(-x)); }
__device__ __forceinline__ float tanh_f(float x){ return 1.f - 2.f/(1.f+__expf(2.f*x)); }

__device__ __forceinline__ void bf8f(uint4 q, float* f){
  f[0]=__uint_as_float(q.x<<16); f[1]=__uint_as_float(q.x&0xFFFF0000u);
  f[2]=__uint_as_float(q.y<<16); f[3]=__uint_as_float(q.y&0xFFFF0000u);
  f[4]=__uint_as_float(q.z<<16); f[5]=__uint_as_float(q.z&0xFFFF0000u);
  f[6]=__uint_as_float(q.w<<16); f[7]=__uint_as_float(q.w&0xFFFF0000u);
}

// ---- dtype-abstracted weight access: BF=true -> bf16 data, BF=false -> fp32 data
template<bool BF>
__device__ __forceinline__ void wload8(const void* base, size_t eoff, float* f){
  if constexpr (BF){
    uint4 q = *(const uint4*)((const u16*)base + eoff);
    bf8f(q, f);
  } else {
    const float4* p = (const float4*)((const float*)base + eoff);
    float4 a = p[0], b = p[1];
    f[0]=a.x; f[1]=a.y; f[2]=a.z; f[3]=a.w;
    f[4]=b.x; f[5]=b.y; f[6]=b.z; f[7]=b.w;
  }
}
template<bool BF>
__device__ __forceinline__ float wld(const void* base, size_t eoff){
  if constexpr (BF) return bf2f(((const u16*)base)[eoff]);
  else              return ((const float*)base)[eoff];
}
// stage 32 weight elements -> LDS as bf16
template<bool BF>
__device__ __forceinline__ void stage32(const void* gbase, size_t eoff, u16* lds){
  if constexpr (BF){
    const uint4* g = (const uint4*)((const u16*)gbase + eoff);
    uint4* l = (uint4*)lds;
    l[0]=g[0]; l[1]=g[1]; l[2]=g[2]; l[3]=g[3];
  } else {
    const float4* g = (const float4*)((const float*)gbase + eoff);
    #pragma unroll
    for(int i=0;i<8;i++){
      float4 v = g[i];
      u16* d = lds + i*4;
      d[0]=f2bf(v.x); d[1]=f2bf(v.y); d[2]=f2bf(v.z); d[3]=f2bf(v.w);
    }
  }
}

// ---------------------------------------------------------------------------
// dtype detector
__global__ __launch_bounds__(64) void k_detect(const void* w, int* flag){
  int tid = threadIdx.x;
  const u16* p = (const u16*)w;
  float m = 0.f;
  #pragma unroll
  for(int i=0;i<16;i++){
    float v = fabsf(bf2f(p[tid*16+i]));
    m = fmaxf(m, v);
  }
  #pragma unroll
  for(int off=32;off;off>>=1) m = fmaxf(m, __shfl_down(m, off));
  if(tid==0) *flag = (m < 16.f) ? 1 : 0;
}

// ---------------------------------------------------------------------------
// Batched embedding -> input-gate projection
template<bool BF>
__device__ void emb_gi_body(const int* toks, int tstride, const void* emb_tab,
                            const void* W_ih, int wstride, const void* b_ih,
                            float* gi)
{
  int blk = blockIdx.x;
  int jc = blk % 6; int b = (blk/6) % BB; int t = blk/(6*BB);
  int tid = threadIdx.x;
  int tok = toks[b*tstride + t];
  __shared__ float emb[EE];
  if(tid < EE) emb[tid] = wld<BF>(emb_tab, (size_t)tok*EE + tid);
  __syncthreads();
  int j = jc*256 + tid;
  float acc = wld<BF>(b_ih, j);
  size_t roff = (size_t)j*wstride;
  #pragma unroll
  for(int i=0;i<8;i++){
    float f[8]; wload8<BF>(W_ih, roff + i*8, f);
    #pragma unroll
    for(int l=0;l<8;l++) acc += emb[i*8+l]*f[l];
  }
  gi[((size_t)t*BB + b)*H3 + j] = acc;
}
__global__ __launch_bounds__(256) void k_emb_gi(
    const int* flag, const int* toks, int tstride, const void* emb_tab,
    const void* W_ih, int wstride, const void* b_ih, float* gi)
{
  if(*flag) emb_gi_body<true>(toks,tstride,emb_tab,W_ih,wstride,b_ih,gi);
  else      emb_gi_body<false>(toks,tstride,emb_tab,W_ih,wstride,b_ih,gi);
}

// ---------------------------------------------------------------------------
// Unified shared memory for the fused persistent kernel. One allocation,
// phases alias it; grid syncs guard all cross-phase WAR hazards.
struct SMem {
  float a[HH];          // es / As / ctx / xs
  float b[HH];          // hs / hsr / vs
  float red[6][256];
  float eS[16];
};

struct EncDecParams {
  const int* flag;
  const void *eWhh, *ebhh;
  const float* enc_gi;
  float* enc_outs;
  const void *aW, *ab, *vW, *vb;
  const void *d0Wih, *d0Whh, *d0bhh;
  const float* trg_gi;
  const void *d1Wih, *d1bih, *d1Whh, *d1bhh;
  float* hE;       // [2][B][H]
  float* h0b;      // [2][B][H]
  float* h1b;      // [2][B][H]
  float* P;        // [B][S][H]
  float* Abuf;     // [B][H]
  float* Cpart;    // [B][8][H]
  float* Ssum;     // [B][8]
  u16* h1_all;     // [MFC][H]
};

// ---- encoder GRU step: block (b,q), thread (jj = tid>>2, t4 = tid&3) ----
template<bool BF>
__device__ void enc_step_dev(SMem& sm, int b, int q, int tid,
                             const float* hin, float* hout,
                             const void* W_hh, const void* b_hh,
                             const float* gi_t, float* enc_outs, int t,
                             float* h0init, float* h1init)
{
  float* hs = sm.b;
  const float* hrow = hin + b*HH;
  hs[tid] = hrow[tid]; hs[tid+256] = hrow[tid+256];
  __syncthreads();
  int jj = tid >> 2, t4 = tid & 3;
  int j = q*64 + jj;
  int k0 = t4*128;
  float ar=0.f, az=0.f, an=0.f;
  size_t orr = (size_t)j*HH + k0;
  size_t oz = (size_t)(512+j)*HH + k0;
  size_t on = (size_t)(1024+j)*HH + k0;
  #pragma unroll 4
  for(int i=0;i<16;i++){
    float f[8];
    wload8<BF>(W_hh, orr + i*8, f);
    #pragma unroll
    for(int l=0;l<8;l++) ar += hs[k0+i*8+l]*f[l];
    wload8<BF>(W_hh, oz + i*8, f);
    #pragma unroll
    for(int l=0;l<8;l++) az += hs[k0+i*8+l]*f[l];
    wload8<BF>(W_hh, on + i*8, f);
    #pragma unroll
    for(int l=0;l<8;l++) an += hs[k0+i*8+l]*f[l];
  }
  sm.red[0][tid]=ar; sm.red[1][tid]=az; sm.red[2][tid]=an;
  __syncthreads();
  if(t4==0){
    float gr = sm.red[0][tid]+sm.red[0][tid+1]+sm.red[0][tid+2]+sm.red[0][tid+3] + wld<BF>(b_hh, j);
    float gz = sm.red[1][tid]+sm.red[1][tid+1]+sm.red[1][tid+2]+sm.red[1][tid+3] + wld<BF>(b_hh, 512+j);
    float gn = sm.red[2][tid]+sm.red[2][tid+1]+sm.red[2][tid+2]+sm.red[2][tid+3] + wld<BF>(b_hh, 1024+j);
    const float* gib = gi_t + b*H3;
    float r = sigm(gib[j] + gr);
    float z = sigm(gib[512+j] + gz);
    float n = tanh_f(gib[1024+j] + r*gn);
    float hn = (1.f - z)*n + z*hs[j];
    hout[b*HH + j] = hn;
    enc_outs[((size_t)b*SS + t)*HH + j] = hn;
    if(h0init){ h0init[b*HH+j] = hn; h1init[b*HH+j] = hn; }
  }
}

// ---- attention enc-projection, one item = (jc,s,b) ----
template<bool BF>
__device__ void attn_proj_dev(SMem& sm, int tid, int item,
                              const float* enc_outs, const void* attn_W,
                              const void* attn_b, float* P)
{
  int jc = item & 1; int s = (item>>1) & (SS-1); int b = item >> 8;
  float* es = sm.a;
  const float* er = enc_outs + ((size_t)b*SS + s)*HH;
  es[tid]=er[tid]; es[tid+256]=er[tid+256];
  __syncthreads();
  int j = jc*256 + tid;
  size_t roff = (size_t)j*1024 + 512;
  float acc = wld<BF>(attn_b, j);
  #pragma unroll 4
  for(int i=0;i<64;i++){
    float f[8]; wload8<BF>(attn_W, roff + i*8, f);
    #pragma unroll
    for(int l=0;l<8;l++) acc += es[i*8+l]*f[l];
  }
  P[((size_t)b*SS+s)*HH + j] = acc;
  __syncthreads();   // WAR guard: next item overwrites es
}

// ---- A[b,j] = attn_W[j,0:512] . h1[b,:], block (b,q), k-split by t4 ----
template<bool BF>
__device__ void dec_A_dev(SMem& sm, int b, int q, int tid,
                          const float* h1, const void* attn_W, float* Abuf)
{
  float* hsr = sm.b;
  hsr[tid]=h1[b*HH+tid]; hsr[tid+256]=h1[b*HH+tid+256];
  __syncthreads();
  int jj = tid>>2, t4 = tid&3, j = q*64+jj, k0 = t4*128;
  size_t roff = (size_t)j*1024 + k0;
  float acc = 0.f;
  #pragma unroll 4
  for(int i=0;i<16;i++){
    float f[8]; wload8<BF>(attn_W, roff + i*8, f);
    #pragma unroll
    for(int l=0;l<8;l++) acc += hsr[k0+i*8+l]*f[l];
  }
  sm.red[0][tid]=acc;
  __syncthreads();
  if(t4==0){
    Abuf[b*HH + j] = sm.red[0][tid]+sm.red[0][tid+1]+sm.red[0][tid+2]+sm.red[0][tid+3];
  }
}

// ---- scores + exp + partial softmax-weighted context, block (b,sb) ----
template<bool BF>
__device__ void dec_scores_dev(SMem& sm, int b, int sb, int tid,
                               const float* Abuf, const float* P,
                               const float* enc_outs, const void* vW,
                               const void* vb, float* Cpart, float* Ssum)
{
  float* As = sm.a;
  float* vs = sm.b;
  As[tid]=Abuf[b*HH+tid]; As[tid+256]=Abuf[b*HH+tid+256];
  vs[tid]=wld<BF>(vW, tid); vs[tid+256]=wld<BF>(vW, tid+256);
  __syncthreads();
  int wave = tid>>6, lane = tid&63;
  float vbf = wld<BF>(vb, 0);
  #pragma unroll
  for(int i=0;i<4;i++){
    int s = sb*16 + wave*4 + i;
    const float* Prow = P + ((size_t)b*SS+s)*HH;
    float part = 0.f;
    #pragma unroll
    for(int kk=0;kk<8;kk++){
      int k = lane + kk*64;
      part += vs[k]*tanh_f(As[k]+Prow[k]);
    }
    #pragma unroll
    for(int off=32;off;off>>=1) part += __shfl_down(part, off);
    if(lane==0) sm.eS[wave*4+i] = __expf(part + vbf);
  }
  __syncthreads();
  for(int j=tid;j<HH;j+=256){
    float c = 0.f;
    #pragma unroll 4
    for(int i=0;i<16;i++) c += sm.eS[i]*enc_outs[((size_t)b*SS + sb*16+i)*HH + j];
    Cpart[((size_t)b*8+sb)*HH + j] = c;
  }
  if(tid==0){ float ss=0.f; for(int i=0;i<16;i++) ss+=sm.eS[i]; Ssum[b*8+sb]=ss; }
}

// ---- decoder GRU layer 0, block (b,q) ----
template<bool BF>
__device__ void dec_h0_dev(SMem& sm, int b, int q, int tid,
                           const float* h0in, float* h0out,
                           const float* Cpart, const float* Ssum,
                           const void* W_ih, const void* W_hh,
                           const void* b_hh, const float* gi_t)
{
  float* ctx = sm.a;
  float* hs  = sm.b;
  const float* hr = h0in + b*HH;
  hs[tid]=hr[tid]; hs[tid+256]=hr[tid+256];
  float ssum = 0.f;
  #pragma unroll
  for(int sb=0;sb<8;sb++) ssum += Ssum[b*8+sb];
  float invS = 1.f/ssum;
  for(int j=tid;j<HH;j+=256){
    float c = 0.f;
    #pragma unroll
    for(int sb=0;sb<8;sb++) c += Cpart[((size_t)b*8+sb)*HH + j];
    ctx[j] = c*invS;
  }
  __syncthreads();
  int jj = tid>>2, t4 = tid&3, j = q*64+jj, k0 = t4*128;
  float pr=0.f,pz=0.f,pn=0.f,qr=0.f,qz=0.f,qn=0.f;
  size_t oir = (size_t)j*EHD + 64 + k0;
  size_t oiz = (size_t)(512+j)*EHD + 64 + k0;
  size_t oin = (size_t)(1024+j)*EHD + 64 + k0;
  size_t ohr = (size_t)j*HH + k0;
  size_t ohz = (size_t)(512+j)*HH + k0;
  size_t ohn = (size_t)(1024+j)*HH + k0;
  #pragma unroll 2
  for(int i=0;i<16;i++){
    float f[8];
    wload8<BF>(W_ih, oir + i*8, f);
    #pragma unroll
    for(int l=0;l<8;l++) pr += ctx[k0+i*8+l]*f[l];
    wload8<BF>(W_ih, oiz + i*8, f);
    #pragma unroll
    for(int l=0;l<8;l++) pz += ctx[k0+i*8+l]*f[l];
    wload8<BF>(W_ih, oin + i*8, f);
    #pragma unroll
    for(int l=0;l<8;l++) pn += ctx[k0+i*8+l]*f[l];
    wload8<BF>(W_hh, ohr + i*8, f);
    #pragma unroll
    for(int l=0;l<8;l++) qr += hs[k0+i*8+l]*f[l];
    wload8<BF>(W_hh, ohz + i*8, f);
    #pragma unroll
    for(int l=0;l<8;l++) qz += hs[k0+i*8+l]*f[l];
    wload8<BF>(W_hh, ohn + i*8, f);
    #pragma unroll
    for(int l=0;l<8;l++) qn += hs[k0+i*8+l]*f[l];
  }
  sm.red[0][tid]=pr; sm.red[1][tid]=pz; sm.red[2][tid]=pn;
  sm.red[3][tid]=qr; sm.red[4][tid]=qz; sm.red[5][tid]=qn;
  __syncthreads();
  if(t4==0){
    float gir = gi_t[b*H3 + j]        + sm.red[0][tid]+sm.red[0][tid+1]+sm.red[0][tid+2]+sm.red[0][tid+3];
    float giz = gi_t[b*H3 + 512 + j]  + sm.red[1][tid]+sm.red[1][tid+1]+sm.red[1][tid+2]+sm.red[1][tid+3];
    float gin = gi_t[b*H3 + 1024 + j] + sm.red[2][tid]+sm.red[2][tid+1]+sm.red[2][tid+2]+sm.red[2][tid+3];
    float ghr = sm.red[3][tid]+sm.red[3][tid+1]+sm.red[3][tid+2]+sm.red[3][tid+3] + wld<BF>(b_hh, j);
    float ghz = sm.red[4][tid]+sm.red[4][tid+1]+sm.red[4][tid+2]+sm.red[4][tid+3] + wld<BF>(b_hh, 512+j);
    float ghn = sm.red[5][tid]+sm.red[5][tid+1]+sm.red[5][tid+2]+sm.red[5][tid+3] + wld<BF>(b_hh, 1024+j);
    float r = sigm(gir+ghr), z = sigm(giz+ghz), n = tanh_f(gin + r*ghn);
    h0out[b*HH + j] = (1.f - z)*n + z*hs[j];
  }
}

// ---- decoder GRU layer 1 (+ bf16 h1 row for fc GEMM), block (b,q) ----
template<bool BF>
__device__ void dec_h1_dev(SMem& sm, int b, int q, int tid,
                           const float* xin, const float* h1in, float* h1out,
                           const void* W_ih, const void* b_ih,
                           const void* W_hh, const void* b_hh,
                           u16* h1_all_t)
{
  float* xs = sm.a;
  float* hs = sm.b;
  const float* xr = xin + b*HH;
  const float* hr = h1in + b*HH;
  xs[tid]=xr[tid]; xs[tid+256]=xr[tid+256];
  hs[tid]=hr[tid]; hs[tid+256]=hr[tid+256];
  __syncthreads();
  int jj = tid>>2, t4 = tid&3, j = q*64+jj, k0 = t4*128;
  float pr=0.f,pz=0.f,pn=0.f,qr=0.f,qz=0.f,qn=0.f;
  size_t oir = (size_t)j*HH + k0;
  size_t oiz = (size_t)(512+j)*HH + k0;
  size_t oin = (size_t)(1024+j)*HH + k0;
  #pragma unroll 2
  for(int i=0;i<16;i++){
    float f[8];
    wload8<BF>(W_ih, oir + i*8, f);
    #pragma unroll
    for(int l=0;l<8;l++) pr += xs[k0+i*8+l]*f[l];
    wload8<BF>(W_ih, oiz + i*8, f);
    #pragma unroll
    for(int l=0;l<8;l++) pz += xs[k0+i*8+l]*f[l];
    wload8<BF>(W_ih, oin + i*8, f);
    #pragma unroll
    for(int l=0;l<8;l++) pn += xs[k0+i*8+l]*f[l];
    wload8<BF>(W_hh, oir + i*8, f);
    #pragma unroll
    for(int l=0;l<8;l++) qr += hs[k0+i*8+l]*f[l];
    wload8<BF>(W_hh, oiz + i*8, f);
    #pragma unroll
    for(int l=0;l<8;l++) qz += hs[k0+i*8+l]*f[l];
    wload8<BF>(W_hh, oin + i*8, f);
    #pragma unroll
    for(int l=0;l<8;l++) qn += hs[k0+i*8+l]*f[l];
  }
  sm.red[0][tid]=pr; sm.red[1][tid]=pz; sm.red[2][tid]=pn;
  sm.red[3][tid]=qr; sm.red[4][tid]=qz; sm.red[5][tid]=qn;
  __syncthreads();
  if(t4==0){
    float gir = wld<BF>(b_ih, j)      + sm.red[0][tid]+sm.red[0][tid+1]+sm.red[0][tid+2]+sm.red[0][tid+3];
    float giz = wld<BF>(b_ih, 512+j)  + sm.red[1][tid]+sm.red[1][tid+1]+sm.red[1][tid+2]+sm.red[1][tid+3];
    float gin = wld<BF>(b_ih, 1024+j) + sm.red[2][tid]+sm.red[2][tid+1]+sm.red[2][tid+2]+sm.red[2][tid+3];
    float ghr = sm.red[3][tid]+sm.red[3][tid+1]+sm.red[3][tid+2]+sm.red[3][tid+3] + wld<BF>(b_hh, j);
    float ghz = sm.red[4][tid]+sm.red[4][tid+1]+sm.red[4][tid+2]+sm.red[4][tid+3] + wld<BF>(b_hh, 512+j);
    float ghn = sm.red[5][tid]+sm.red[5][tid+1]+sm.red[5][tid+2]+sm.red[5][tid+3] + wld<BF>(b_hh, 1024+j);
    float r = sigm(gir+ghr), z = sigm(giz+ghz), n = tanh_f(gin + r*ghn);
    float hn = (1.f - z)*n + z*hs[j];
    h1out[b*HH + j] = hn;
    h1_all_t[b*HH + j] = f2bf(hn);
  }
}

// ---------------------------------------------------------------------------
// Fused persistent encoder + attn-proj + decoder. 256 blocks x 256 threads,
// cooperative launch; grid.sync() between dependent phases.
template<bool BF>
__device__ void encdec_body(const EncDecParams& p, cg::grid_group& g, SMem& sm)
{
  int blk = blockIdx.x, tid = threadIdx.x;
  int b = blk >> 3, q = blk & 7;

  // ---- encoder: 128 steps, 1 grid sync each ----
  for(int t=0;t<SS;t++){
    enc_step_dev<BF>(sm, b, q, tid,
        p.hE + (t&1)*BB*HH, p.hE + ((t+1)&1)*BB*HH,
        p.eWhh, p.ebhh, p.enc_gi + (size_t)t*BB*H3, p.enc_outs, t,
        (t==SS-1)? p.h0b : (float*)nullptr,
        (t==SS-1)? p.h1b : (float*)nullptr);
    g.sync();
  }

  // ---- step-invariant attention enc-projection: 8192 items over 256 blocks ----
  for(int it=0; it<(BB*SS*2)/256; it++){
    attn_proj_dev<BF>(sm, tid, it*256 + blk, p.enc_outs, p.aW, p.ab, p.P);
  }
  g.sync();

  // ---- decoder: 63 steps x 4 phases ----
  for(int t=0;t<TD;t++){
    int pi = t&1, po = (t+1)&1;
    dec_A_dev<BF>(sm, b, q, tid, p.h1b + pi*BB*HH, p.aW, p.Abuf);
    g.sync();
    dec_scores_dev<BF>(sm, b, q, tid, p.Abuf, p.P, p.enc_outs, p.vW, p.vb,
                       p.Cpart, p.Ssum);
    g.sync();
    dec_h0_dev<BF>(sm, b, q, tid, p.h0b + pi*BB*HH, p.h0b + po*BB*HH,
                   p.Cpart, p.Ssum, p.d0Wih, p.d0Whh, p.d0bhh,
                   p.trg_gi + (size_t)t*BB*H3);
    g.sync();
    dec_h1_dev<BF>(sm, b, q, tid, p.h0b + po*BB*HH, p.h1b + pi*BB*HH,
                   p.h1b + po*BB*HH, p.d1Wih, p.d1bih, p.d1Whh, p.d1bhh,
                   p.h1_all + (size_t)t*BB*HH);
    g.sync();
  }
}

__global__ __launch_bounds__(256) void k_encdec(EncDecParams p)
{
  cg::grid_group g = cg::this_grid();
  __shared__ SMem sm;
  if(*p.flag) encdec_body<true>(p, g, sm);
  else        encdec_body<false>(p, g, sm);
}

// ---------------------------------------------------------------------------
// out[:, 0, :] = 0.   grid = B*V/256
__global__ __launch_bounds__(256) void k_zero_t0(const int* flag, void* out){
  int idx = blockIdx.x*256 + threadIdx.x;
  int b = idx / VV, v = idx - b*VV;
  size_t o = (size_t)b*TT*VV + v;
  if(*flag) ((u16*)out)[o] = 0;
  else      ((float*)out)[o] = 0.f;
}

// ---------------------------------------------------------------------------
// Batched fc GEMM: C[m,n] = A[m,:] . W[n,:] + b[n]; m = t*32+b -> out[b,t+1,n]
template<bool BF>
__device__ void fc_body(const u16* A, const void* W, const void* bias, void* out)
{
  __shared__ u16 As[128*72];   // +8 bf16 pad per row
  __shared__ u16 Bs[128*72];
  int bm = blockIdx.x, bn = blockIdx.y;
  int tid = threadIdx.x;
  int wave = tid>>6, lane = tid&63;
  int wr = wave>>1, wc = wave&1;
  f32x4 acc[4][4];
  f32x4 zero = {0.f,0.f,0.f,0.f};
  #pragma unroll
  for(int i=0;i<4;i++)
    #pragma unroll
    for(int j=0;j<4;j++) acc[i][j]=zero;

  int row = tid>>1, half = tid&1;
  const size_t gA = (size_t)(bm*128 + row)*512 + half*32;
  const size_t gB = (size_t)(bn*128 + row)*512 + half*32;
  u16* lA = As + row*72 + half*32;
  u16* lB = Bs + row*72 + half*32;

  for(int kk=0;kk<8;kk++){
    int k0 = kk*64;
    if(kk) __syncthreads();
    stage32<true>(A, gA + k0, lA);
    stage32<BF>(W, gB + k0, lB);
    __syncthreads();
    #pragma unroll
    for(int ks=0;ks<2;ks++){
      int kof = ks*32 + (lane>>4)*8;
      bf16x8 af[4], bfv[4];
      #pragma unroll
      for(int i=0;i<4;i++){
        af[i]  = *(const bf16x8*)(As + (wr*64 + i*16 + (lane&15))*72 + kof);
        bfv[i] = *(const bf16x8*)(Bs + (wc*64 + i*16 + (lane&15))*72 + kof);
      }
      #pragma unroll
      for(int i=0;i<4;i++)
        #pragma unroll
        for(int j=0;j<4;j++)
          acc[i][j] = __builtin_amdgcn_mfma_f32_16x16x32_bf16(af[i], bfv[j], acc[i][j], 0, 0, 0);
    }
  }
  // epilogue: C/D layout col = lane&15, row = (lane>>4)*4 + r   [m89-verified]
  int quad = lane>>4, col = lane&15;
  #pragma unroll
  for(int j=0;j<4;j++){
    int n = bn*128 + wc*64 + j*16 + col;
    float bsv = wld<BF>(bias, n);
    #pragma unroll
    for(int i=0;i<4;i++){
      int mbase = bm*128 + wr*64 + i*16 + quad*4;
      #pragma unroll
      for(int r=0;r<4;r++){
        int m = mbase + r;
        if(m < TD*BB){
          int t = m >> 5, b = m & 31;
          size_t o = ((size_t)(b*TT + t + 1))*VV + n;
          float v = acc[i][j][r] + bsv;
          if constexpr (BF) ((u16*)out)[o] = f2bf(v);
          else              ((float*)out)[o] = v;
        }
      }
    }
  }
}
__global__ __launch_bounds__(256) void k_fc(
  const int* flag, const u16* A, const void* W, const void* bias, void* out)
{
  if(*flag) fc_body<true>(A, W, bias, out);
  else      fc_body<false>(A, W, bias, out);
}

// ---------------------------------------------------------------------------
extern "C" void kernel_launch(void* const* d_in, const int* in_sizes, int n_in,
                              void* d_out, int out_size, void* d_ws, size_t ws_size,
                              hipStream_t stream)
{
  const int* src = (const int*)d_in[0];
  const int* trg = (const int*)d_in[1];
  const void* src_emb = d_in[2];
  const void* trg_emb = d_in[3];
  const void* eWih = d_in[4];
  const void* eWhh = d_in[5];
  const void* ebih = d_in[6];
  const void* ebhh = d_in[7];
  const void* d0Wih = d_in[8];
  const void* d0Whh = d_in[9];
  const void* d0bih = d_in[10];
  const void* d0bhh = d_in[11];
  const void* d1Wih = d_in[12];
  const void* d1Whh = d_in[13];
  const void* d1bih = d_in[14];
  const void* d1bhh = d_in[15];
  const void* aW  = d_in[16];
  const void* ab  = d_in[17];
  const void* vW  = d_in[18];
  const void* vb  = d_in[19];
  const void* fcW = d_in[20];
  const void* fcb = d_in[21];

  char* w = (char*)d_ws;
  int*   flag    = (int*)w;   w += 16;
  float* enc_gi  = (float*)w; w += (size_t)SS*BB*H3*4;   // 25.2 MB
  float* trg_gi  = (float*)w; w += (size_t)TD*BB*H3*4;   // 12.4 MB
  float* enc_outs= (float*)w; w += (size_t)BB*SS*HH*4;   // 8.4 MB
  float* P       = (float*)w; w += (size_t)BB*SS*HH*4;   // 8.4 MB
  float* hE      = (float*)w; w += (size_t)2*BB*HH*4;
  float* h0b     = (float*)w; w += (size_t)2*BB*HH*4;
  float* h1b     = (float*)w; w += (size_t)2*BB*HH*4;
  float* Abuf    = (float*)w; w += (size_t)BB*HH*4;
  float* Cpart   = (float*)w; w += (size_t)BB*8*HH*4;
  float* Ssum    = (float*)w; w += (size_t)BB*8*4;
  u16*   h1_all  = (u16*)w;   w += (size_t)MFC*HH*2;

  // init (ws is poisoned 0xAA before every call)
  hipMemsetAsync(hE, 0, BB*HH*4, stream);                        // encoder h0 = 0
  hipMemsetAsync(h1_all + (size_t)TD*BB*HH, 0, 32*HH*2, stream); // fc pad rows

  // dtype detection (writes flag)
  k_detect<<<1,64,0,stream>>>(fcW, flag);

  // batched input-gate projections (parallel work, single launches)
  k_emb_gi<<<SS*BB*6, 256, 0, stream>>>(flag, src, SS, src_emb, eWih, EE, ebih, enc_gi);
  k_emb_gi<<<TD*BB*6, 256, 0, stream>>>(flag, trg, TT, trg_emb, d0Wih, EHD, d0bih, trg_gi);

  // fused persistent encoder + attn-proj + decoder (cooperative)
  EncDecParams prm;
  prm.flag = flag;
  prm.eWhh = eWhh; prm.ebhh = ebhh;
  prm.enc_gi = enc_gi;
  prm.enc_outs = enc_outs;
  prm.aW = aW; prm.ab = ab; prm.vW = vW; prm.vb = vb;
  prm.d0Wih = d0Wih; prm.d0Whh = d0Whh; prm.d0bhh = d0bhh;
  prm.trg_gi = trg_gi;
  prm.d1Wih = d1Wih; prm.d1bih = d1bih; prm.d1Whh = d1Whh; prm.d1bhh = d1bhh;
  prm.hE = hE; prm.h0b = h0b; prm.h1b = h1b;
  prm.P = P; prm.Abuf = Abuf; prm.Cpart = Cpart; prm.Ssum = Ssum;
  prm.h1_all = h1_all;

  void* kargs[] = { (void*)&prm };
  hipLaunchCooperativeKernel(reinterpret_cast<void*>(&k_encdec),
                             dim3(256), dim3(256), kargs, 0, stream);

  // outputs
  k_zero_t0<<<(BB*VV)/256, 256, 0, stream>>>(flag, d_out);
  dim3 g(16, 250);
  k_fc<<<g, 256, 0, stream>>>(flag, h1_all, fcW, fcb, d_out);
}

// Round 3
// 8419.029 us; speedup vs baseline: 2.0913x; 2.0913x over previous
//
#include <hip/hip_runtime.h>
#include <hip/hip_bf16.h>

// Problem dims
#define BB 32
#define SS 128
#define TT 64
#define EE 64
#define HH 512
#define H3 1536
#define VV 32000
#define EHD 576      // E + H (dec0 input width)
#define TD 63        // decoder steps
#define MFC 2048     // padded M for fc GEMM (63*32 = 2016 real rows)

typedef unsigned short u16;
typedef unsigned int   u32;

typedef __attribute__((ext_vector_type(8))) short bf16x8;
typedef __attribute__((ext_vector_type(4))) float f32x4;

__device__ __forceinline__ float bf2f(u16 u){ return __uint_as_float(((u32)u)<<16); }
__device__ __forceinline__ u16 f2bf(float f){
  u32 u = __float_as_uint(f);
  u += 0x7FFFu + ((u>>16)&1u);       // RNE
  return (u16)(u>>16);
}
__device__ __forceinline__ float sigm(float x){ return 1.f/(1.f+__expf(-x)); }
__device__ __forceinline__ float tanh_f(float x){ return 1.f - 2.f/(1.f+__expf(2.f*x)); }

__device__ __forceinline__ void bf8f(uint4 q, float* f){
  f[0]=__uint_as_float(q.x<<16); f[1]=__uint_as_float(q.x&0xFFFF0000u);
  f[2]=__uint_as_float(q.y<<16); f[3]=__uint_as_float(q.y&0xFFFF0000u);
  f[4]=__uint_as_float(q.z<<16); f[5]=__uint_as_float(q.z&0xFFFF0000u);
  f[6]=__uint_as_float(q.w<<16); f[7]=__uint_as_float(q.w&0xFFFF0000u);
}

// ---- dtype-abstracted weight access: BF=true -> bf16 data, BF=false -> fp32 data
template<bool BF>
__device__ __forceinline__ void wload8(const void* base, size_t eoff, float* f){
  if constexpr (BF){
    uint4 q = *(const uint4*)((const u16*)base + eoff);
    bf8f(q, f);
  } else {
    const float4* p = (const float4*)((const float*)base + eoff);
    float4 a = p[0], b = p[1];
    f[0]=a.x; f[1]=a.y; f[2]=a.z; f[3]=a.w;
    f[4]=b.x; f[5]=b.y; f[6]=b.z; f[7]=b.w;
  }
}
template<bool BF>
__device__ __forceinline__ float wld(const void* base, size_t eoff){
  if constexpr (BF) return bf2f(((const u16*)base)[eoff]);
  else              return ((const float*)base)[eoff];
}
// stage 32 weight elements -> LDS as bf16
template<bool BF>
__device__ __forceinline__ void stage32(const void* gbase, size_t eoff, u16* lds){
  if constexpr (BF){
    const uint4* g = (const uint4*)((const u16*)gbase + eoff);
    uint4* l = (uint4*)lds;
    l[0]=g[0]; l[1]=g[1]; l[2]=g[2]; l[3]=g[3];
  } else {
    const float4* g = (const float4*)((const float*)gbase + eoff);
    #pragma unroll
    for(int i=0;i<8;i++){
      float4 v = g[i];
      u16* d = lds + i*4;
      d[0]=f2bf(v.x); d[1]=f2bf(v.y); d[2]=f2bf(v.z); d[3]=f2bf(v.w);
    }
  }
}

// ---------------------------------------------------------------------------
// Per-batch 8-block barrier. Monotonic counter, one cacheline per batch.
// tid0: release-add, relaxed spin, acquire fence. Arrival implies the block
// finished its phase (syncthreads first), so one barrier covers RAW and WAR.
__device__ __forceinline__ void bbar(unsigned int* ctr, int tid, unsigned int target){
  __syncthreads();
  if(tid==0){
    __hip_atomic_fetch_add(ctr, 1u, __ATOMIC_RELEASE, __HIP_MEMORY_SCOPE_AGENT);
    while(__hip_atomic_load(ctr, __ATOMIC_RELAXED, __HIP_MEMORY_SCOPE_AGENT) < target){
      __builtin_amdgcn_s_sleep(1);
    }
    __builtin_amdgcn_fence(__ATOMIC_ACQUIRE, "agent");
  }
  __syncthreads();
}

// ---------------------------------------------------------------------------
// dtype detector
__global__ __launch_bounds__(64) void k_detect(const void* w, int* flag){
  int tid = threadIdx.x;
  const u16* p = (const u16*)w;
  float m = 0.f;
  #pragma unroll
  for(int i=0;i<16;i++){
    float v = fabsf(bf2f(p[tid*16+i]));
    m = fmaxf(m, v);
  }
  #pragma unroll
  for(int off=32;off;off>>=1) m = fmaxf(m, __shfl_down(m, off));
  if(tid==0) *flag = (m < 16.f) ? 1 : 0;
}

// ---------------------------------------------------------------------------
// Batched embedding -> input-gate projection
template<bool BF>
__device__ void emb_gi_body(const int* toks, int tstride, const void* emb_tab,
                            const void* W_ih, int wstride, const void* b_ih,
                            float* gi)
{
  int blk = blockIdx.x;
  int jc = blk % 6; int b = (blk/6) % BB; int t = blk/(6*BB);
  int tid = threadIdx.x;
  int tok = toks[b*tstride + t];
  __shared__ float emb[EE];
  if(tid < EE) emb[tid] = wld<BF>(emb_tab, (size_t)tok*EE + tid);
  __syncthreads();
  int j = jc*256 + tid;
  float acc = wld<BF>(b_ih, j);
  size_t roff = (size_t)j*wstride;
  #pragma unroll
  for(int i=0;i<8;i++){
    float f[8]; wload8<BF>(W_ih, roff + i*8, f);
    #pragma unroll
    for(int l=0;l<8;l++) acc += emb[i*8+l]*f[l];
  }
  gi[((size_t)t*BB + b)*H3 + j] = acc;
}
__global__ __launch_bounds__(256) void k_emb_gi(
    const int* flag, const int* toks, int tstride, const void* emb_tab,
    const void* W_ih, int wstride, const void* b_ih, float* gi)
{
  if(*flag) emb_gi_body<true>(toks,tstride,emb_tab,W_ih,wstride,b_ih,gi);
  else      emb_gi_body<false>(toks,tstride,emb_tab,W_ih,wstride,b_ih,gi);
}

// ---------------------------------------------------------------------------
// Unified shared memory for the fused persistent kernel.
struct SMem {
  union {
    struct {
      float a[HH];          // As / ctx / xs
      float b[HH];          // hs / hsr / vs
      float red[6][256];
      float eS[16];
    };
    float es16[16][520];    // attn_proj staging: 16 enc rows (+8 pad)
  };
};

struct EncDecParams {
  const int* flag;
  const void *eWhh, *ebhh;
  const float* enc_gi;
  float* enc_outs;
  const void *aW, *ab, *vW, *vb;
  const void *d0Wih, *d0Whh, *d0bhh;
  const float* trg_gi;
  const void *d1Wih, *d1bih, *d1Whh, *d1bhh;
  float* hE;       // [2][B][H]
  float* h0b;      // [2][B][H]
  float* h1b;      // [2][B][H]
  float* P;        // [B][S][H]
  float* Abuf;     // [B][H]
  float* Cpart;    // [B][8][H]
  float* Ssum;     // [B][8]
  u16* h1_all;     // [MFC][H]
  unsigned int* bctr;  // [B] barrier counters, 64-int stride
};

// ---- encoder GRU step: block (b,q), thread (jj = tid>>2, t4 = tid&3) ----
template<bool BF>
__device__ void enc_step_dev(SMem& sm, int b, int q, int tid,
                             const float* hin, float* hout,
                             const void* W_hh, const void* b_hh,
                             const float* gi_t, float* enc_outs, int t,
                             float* h0init, float* h1init)
{
  float* hs = sm.b;
  const float* hrow = hin + b*HH;
  hs[tid] = hrow[tid]; hs[tid+256] = hrow[tid+256];
  __syncthreads();
  int jj = tid >> 2, t4 = tid & 3;
  int j = q*64 + jj;
  int k0 = t4*128;
  float ar=0.f, az=0.f, an=0.f;
  size_t orr = (size_t)j*HH + k0;
  size_t oz = (size_t)(512+j)*HH + k0;
  size_t on = (size_t)(1024+j)*HH + k0;
  #pragma unroll 4
  for(int i=0;i<16;i++){
    float f[8];
    wload8<BF>(W_hh, orr + i*8, f);
    #pragma unroll
    for(int l=0;l<8;l++) ar += hs[k0+i*8+l]*f[l];
    wload8<BF>(W_hh, oz + i*8, f);
    #pragma unroll
    for(int l=0;l<8;l++) az += hs[k0+i*8+l]*f[l];
    wload8<BF>(W_hh, on + i*8, f);
    #pragma unroll
    for(int l=0;l<8;l++) an += hs[k0+i*8+l]*f[l];
  }
  sm.red[0][tid]=ar; sm.red[1][tid]=az; sm.red[2][tid]=an;
  __syncthreads();
  if(t4==0){
    float gr = sm.red[0][tid]+sm.red[0][tid+1]+sm.red[0][tid+2]+sm.red[0][tid+3] + wld<BF>(b_hh, j);
    float gz = sm.red[1][tid]+sm.red[1][tid+1]+sm.red[1][tid+2]+sm.red[1][tid+3] + wld<BF>(b_hh, 512+j);
    float gn = sm.red[2][tid]+sm.red[2][tid+1]+sm.red[2][tid+2]+sm.red[2][tid+3] + wld<BF>(b_hh, 1024+j);
    const float* gib = gi_t + b*H3;
    float r = sigm(gib[j] + gr);
    float z = sigm(gib[512+j] + gz);
    float n = tanh_f(gib[1024+j] + r*gn);
    float hn = (1.f - z)*n + z*hs[j];
    hout[b*HH + j] = hn;
    enc_outs[((size_t)b*SS + t)*HH + j] = hn;
    if(h0init){ h0init[b*HH+j] = hn; h1init[b*HH+j] = hn; }
  }
}

// ---- attention enc-projection for this block's 16 s-rows of batch b ----
// Stage rows in LDS once; each thread owns 2 weight rows j, computes 16 dots.
template<bool BF>
__device__ void attn_proj_blk(SMem& sm, int b, int q, int tid,
                              const float* enc_outs, const void* attn_W,
                              const void* attn_b, float* P)
{
  #pragma unroll 4
  for(int i=0;i<16;i++){
    const float* er = enc_outs + ((size_t)b*SS + q*16 + i)*HH;
    sm.es16[i][tid]     = er[tid];
    sm.es16[i][tid+256] = er[tid+256];
  }
  __syncthreads();
  #pragma unroll
  for(int rr=0; rr<2; rr++){
    int j = rr*256 + tid;
    float bj = wld<BF>(attn_b, j);
    float acc[16];
    #pragma unroll
    for(int i=0;i<16;i++) acc[i] = bj;
    size_t roff = (size_t)j*1024 + 512;
    for(int kk=0;kk<64;kk++){
      float f[8]; wload8<BF>(attn_W, roff + kk*8, f);
      #pragma unroll
      for(int i=0;i<16;i++){
        const float4* e4 = (const float4*)(&sm.es16[i][kk*8]);
        float4 ea = e4[0], eb = e4[1];
        acc[i] += ea.x*f[0]+ea.y*f[1]+ea.z*f[2]+ea.w*f[3]
                + eb.x*f[4]+eb.y*f[5]+eb.z*f[6]+eb.w*f[7];
      }
    }
    #pragma unroll
    for(int i=0;i<16;i++)
      P[((size_t)b*SS + q*16 + i)*HH + j] = acc[i];
  }
  __syncthreads();
}

// ---- A[b,j] = attn_W[j,0:512] . h1[b,:], block (b,q), k-split by t4 ----
template<bool BF>
__device__ void dec_A_dev(SMem& sm, int b, int q, int tid,
                          const float* h1, const void* attn_W, float* Abuf)
{
  float* hsr = sm.b;
  hsr[tid]=h1[b*HH+tid]; hsr[tid+256]=h1[b*HH+tid+256];
  __syncthreads();
  int jj = tid>>2, t4 = tid&3, j = q*64+jj, k0 = t4*128;
  size_t roff = (size_t)j*1024 + k0;
  float acc = 0.f;
  #pragma unroll 4
  for(int i=0;i<16;i++){
    float f[8]; wload8<BF>(attn_W, roff + i*8, f);
    #pragma unroll
    for(int l=0;l<8;l++) acc += hsr[k0+i*8+l]*f[l];
  }
  sm.red[0][tid]=acc;
  __syncthreads();
  if(t4==0){
    Abuf[b*HH + j] = sm.red[0][tid]+sm.red[0][tid+1]+sm.red[0][tid+2]+sm.red[0][tid+3];
  }
}

// ---- scores + exp + partial softmax-weighted context, block (b, sb=q) ----
template<bool BF>
__device__ void dec_scores_dev(SMem& sm, int b, int sb, int tid,
                               const float* Abuf, const float* P,
                               const float* enc_outs, const void* vW,
                               const void* vb, float* Cpart, float* Ssum)
{
  float* As = sm.a;
  float* vs = sm.b;
  As[tid]=Abuf[b*HH+tid]; As[tid+256]=Abuf[b*HH+tid+256];
  vs[tid]=wld<BF>(vW, tid); vs[tid+256]=wld<BF>(vW, tid+256);
  __syncthreads();
  int wave = tid>>6, lane = tid&63;
  float vbf = wld<BF>(vb, 0);
  #pragma unroll
  for(int i=0;i<4;i++){
    int s = sb*16 + wave*4 + i;
    const float* Prow = P + ((size_t)b*SS+s)*HH;
    float part = 0.f;
    #pragma unroll
    for(int kk=0;kk<8;kk++){
      int k = lane + kk*64;
      part += vs[k]*tanh_f(As[k]+Prow[k]);
    }
    #pragma unroll
    for(int off=32;off;off>>=1) part += __shfl_down(part, off);
    if(lane==0) sm.eS[wave*4+i] = __expf(part + vbf);
  }
  __syncthreads();
  for(int j=tid;j<HH;j+=256){
    float c = 0.f;
    #pragma unroll 4
    for(int i=0;i<16;i++) c += sm.eS[i]*enc_outs[((size_t)b*SS + sb*16+i)*HH + j];
    Cpart[((size_t)b*8+sb)*HH + j] = c;
  }
  if(tid==0){ float ss=0.f; for(int i=0;i<16;i++) ss+=sm.eS[i]; Ssum[b*8+sb]=ss; }
}

// ---- decoder GRU layer 0, block (b,q) ----
template<bool BF>
__device__ void dec_h0_dev(SMem& sm, int b, int q, int tid,
                           const float* h0in, float* h0out,
                           const float* Cpart, const float* Ssum,
                           const void* W_ih, const void* W_hh,
                           const void* b_hh, const float* gi_t)
{
  float* ctx = sm.a;
  float* hs  = sm.b;
  const float* hr = h0in + b*HH;
  hs[tid]=hr[tid]; hs[tid+256]=hr[tid+256];
  float ssum = 0.f;
  #pragma unroll
  for(int sb=0;sb<8;sb++) ssum += Ssum[b*8+sb];
  float invS = 1.f/ssum;
  for(int j=tid;j<HH;j+=256){
    float c = 0.f;
    #pragma unroll
    for(int sb=0;sb<8;sb++) c += Cpart[((size_t)b*8+sb)*HH + j];
    ctx[j] = c*invS;
  }
  __syncthreads();
  int jj = tid>>2, t4 = tid&3, j = q*64+jj, k0 = t4*128;
  float pr=0.f,pz=0.f,pn=0.f,qr=0.f,qz=0.f,qn=0.f;
  size_t oir = (size_t)j*EHD + 64 + k0;
  size_t oiz = (size_t)(512+j)*EHD + 64 + k0;
  size_t oin = (size_t)(1024+j)*EHD + 64 + k0;
  size_t ohr = (size_t)j*HH + k0;
  size_t ohz = (size_t)(512+j)*HH + k0;
  size_t ohn = (size_t)(1024+j)*HH + k0;
  #pragma unroll 2
  for(int i=0;i<16;i++){
    float f[8];
    wload8<BF>(W_ih, oir + i*8, f);
    #pragma unroll
    for(int l=0;l<8;l++) pr += ctx[k0+i*8+l]*f[l];
    wload8<BF>(W_ih, oiz + i*8, f);
    #pragma unroll
    for(int l=0;l<8;l++) pz += ctx[k0+i*8+l]*f[l];
    wload8<BF>(W_ih, oin + i*8, f);
    #pragma unroll
    for(int l=0;l<8;l++) pn += ctx[k0+i*8+l]*f[l];
    wload8<BF>(W_hh, ohr + i*8, f);
    #pragma unroll
    for(int l=0;l<8;l++) qr += hs[k0+i*8+l]*f[l];
    wload8<BF>(W_hh, ohz + i*8, f);
    #pragma unroll
    for(int l=0;l<8;l++) qz += hs[k0+i*8+l]*f[l];
    wload8<BF>(W_hh, ohn + i*8, f);
    #pragma unroll
    for(int l=0;l<8;l++) qn += hs[k0+i*8+l]*f[l];
  }
  sm.red[0][tid]=pr; sm.red[1][tid]=pz; sm.red[2][tid]=pn;
  sm.red[3][tid]=qr; sm.red[4][tid]=qz; sm.red[5][tid]=qn;
  __syncthreads();
  if(t4==0){
    float gir = gi_t[b*H3 + j]        + sm.red[0][tid]+sm.red[0][tid+1]+sm.red[0][tid+2]+sm.red[0][tid+3];
    float giz = gi_t[b*H3 + 512 + j]  + sm.red[1][tid]+sm.red[1][tid+1]+sm.red[1][tid+2]+sm.red[1][tid+3];
    float gin = gi_t[b*H3 + 1024 + j] + sm.red[2][tid]+sm.red[2][tid+1]+sm.red[2][tid+2]+sm.red[2][tid+3];
    float ghr = sm.red[3][tid]+sm.red[3][tid+1]+sm.red[3][tid+2]+sm.red[3][tid+3] + wld<BF>(b_hh, j);
    float ghz = sm.red[4][tid]+sm.red[4][tid+1]+sm.red[4][tid+2]+sm.red[4][tid+3] + wld<BF>(b_hh, 512+j);
    float ghn = sm.red[5][tid]+sm.red[5][tid+1]+sm.red[5][tid+2]+sm.red[5][tid+3] + wld<BF>(b_hh, 1024+j);
    float r = sigm(gir+ghr), z = sigm(giz+ghz), n = tanh_f(gin + r*ghn);
    h0out[b*HH + j] = (1.f - z)*n + z*hs[j];
  }
}

// ---- decoder GRU layer 1 (+ bf16 h1 row for fc GEMM), block (b,q) ----
template<bool BF>
__device__ void dec_h1_dev(SMem& sm, int b, int q, int tid,
                           const float* xin, const float* h1in, float* h1out,
                           const void* W_ih, const void* b_ih,
                           const void* W_hh, const void* b_hh,
                           u16* h1_all_t)
{
  float* xs = sm.a;
  float* hs = sm.b;
  const float* xr = xin + b*HH;
  const float* hr = h1in + b*HH;
  xs[tid]=xr[tid]; xs[tid+256]=xr[tid+256];
  hs[tid]=hr[tid]; hs[tid+256]=hr[tid+256];
  __syncthreads();
  int jj = tid>>2, t4 = tid&3, j = q*64+jj, k0 = t4*128;
  float pr=0.f,pz=0.f,pn=0.f,qr=0.f,qz=0.f,qn=0.f;
  size_t oir = (size_t)j*HH + k0;
  size_t oiz = (size_t)(512+j)*HH + k0;
  size_t oin = (size_t)(1024+j)*HH + k0;
  #pragma unroll 2
  for(int i=0;i<16;i++){
    float f[8];
    wload8<BF>(W_ih, oir + i*8, f);
    #pragma unroll
    for(int l=0;l<8;l++) pr += xs[k0+i*8+l]*f[l];
    wload8<BF>(W_ih, oiz + i*8, f);
    #pragma unroll
    for(int l=0;l<8;l++) pz += xs[k0+i*8+l]*f[l];
    wload8<BF>(W_ih, oin + i*8, f);
    #pragma unroll
    for(int l=0;l<8;l++) pn += xs[k0+i*8+l]*f[l];
    wload8<BF>(W_hh, oir + i*8, f);
    #pragma unroll
    for(int l=0;l<8;l++) qr += hs[k0+i*8+l]*f[l];
    wload8<BF>(W_hh, oiz + i*8, f);
    #pragma unroll
    for(int l=0;l<8;l++) qz += hs[k0+i*8+l]*f[l];
    wload8<BF>(W_hh, oin + i*8, f);
    #pragma unroll
    for(int l=0;l<8;l++) qn += hs[k0+i*8+l]*f[l];
  }
  sm.red[0][tid]=pr; sm.red[1][tid]=pz; sm.red[2][tid]=pn;
  sm.red[3][tid]=qr; sm.red[4][tid]=qz; sm.red[5][tid]=qn;
  __syncthreads();
  if(t4==0){
    float gir = wld<BF>(b_ih, j)      + sm.red[0][tid]+sm.red[0][tid+1]+sm.red[0][tid+2]+sm.red[0][tid+3];
    float giz = wld<BF>(b_ih, 512+j)  + sm.red[1][tid]+sm.red[1][tid+1]+sm.red[1][tid+2]+sm.red[1][tid+3];
    float gin = wld<BF>(b_ih, 1024+j) + sm.red[2][tid]+sm.red[2][tid+1]+sm.red[2][tid+2]+sm.red[2][tid+3];
    float ghr = sm.red[3][tid]+sm.red[3][tid+1]+sm.red[3][tid+2]+sm.red[3][tid+3] + wld<BF>(b_hh, j);
    float ghz = sm.red[4][tid]+sm.red[4][tid+1]+sm.red[4][tid+2]+sm.red[4][tid+3] + wld<BF>(b_hh, 512+j);
    float ghn = sm.red[5][tid]+sm.red[5][tid+1]+sm.red[5][tid+2]+sm.red[5][tid+3] + wld<BF>(b_hh, 1024+j);
    float r = sigm(gir+ghr), z = sigm(giz+ghz), n = tanh_f(gin + r*ghn);
    float hn = (1.f - z)*n + z*hs[j];
    h1out[b*HH + j] = hn;
    h1_all_t[b*HH + j] = f2bf(hn);
  }
}

// ---------------------------------------------------------------------------
// Fused persistent encoder + attn-proj + decoder. 256 blocks x 256 threads.
// Each batch b is owned by 8 blocks (q=0..7); batches are fully independent,
// synced only via the per-batch 8-block barrier. No grid-wide sync anywhere.
template<bool BF>
__device__ void encdec_body(const EncDecParams& p, SMem& sm)
{
  int blk = blockIdx.x, tid = threadIdx.x;
  int b = blk & 31, q = blk >> 5;        // same-batch blocks 32 apart -> same XCD (heuristic)
  unsigned int* ctr = p.bctr + b*64;     // one cacheline per batch
  unsigned int bt = 0;

  // ---- encoder: 128 steps, per-batch barrier each ----
  for(int t=0;t<SS;t++){
    enc_step_dev<BF>(sm, b, q, tid,
        p.hE + (t&1)*BB*HH, p.hE + ((t+1)&1)*BB*HH,
        p.eWhh, p.ebhh, p.enc_gi + (size_t)t*BB*H3, p.enc_outs, t,
        (t==SS-1)? p.h0b : (float*)nullptr,
        (t==SS-1)? p.h1b : (float*)nullptr);
    bt += 8; bbar(ctr, tid, bt);
  }

  // ---- step-invariant attention enc-projection (this block's 16 s-rows) ----
  attn_proj_blk<BF>(sm, b, q, tid, p.enc_outs, p.aW, p.ab, p.P);
  bt += 8; bbar(ctr, tid, bt);

  // ---- decoder: 63 steps x 4 phases, per-batch barriers ----
  for(int t=0;t<TD;t++){
    int pi = t&1, po = (t+1)&1;
    dec_A_dev<BF>(sm, b, q, tid, p.h1b + pi*BB*HH, p.aW, p.Abuf);
    bt += 8; bbar(ctr, tid, bt);
    dec_scores_dev<BF>(sm, b, q, tid, p.Abuf, p.P, p.enc_outs, p.vW, p.vb,
                       p.Cpart, p.Ssum);
    bt += 8; bbar(ctr, tid, bt);
    dec_h0_dev<BF>(sm, b, q, tid, p.h0b + pi*BB*HH, p.h0b + po*BB*HH,
                   p.Cpart, p.Ssum, p.d0Wih, p.d0Whh, p.d0bhh,
                   p.trg_gi + (size_t)t*BB*H3);
    bt += 8; bbar(ctr, tid, bt);
    dec_h1_dev<BF>(sm, b, q, tid, p.h0b + po*BB*HH, p.h1b + pi*BB*HH,
                   p.h1b + po*BB*HH, p.d1Wih, p.d1bih, p.d1Whh, p.d1bhh,
                   p.h1_all + (size_t)t*BB*HH);
    bt += 8; bbar(ctr, tid, bt);
  }
}

__global__ __launch_bounds__(256) void k_encdec(EncDecParams p)
{
  __shared__ SMem sm;
  if(*p.flag) encdec_body<true>(p, sm);
  else        encdec_body<false>(p, sm);
}

// ---------------------------------------------------------------------------
// out[:, 0, :] = 0.   grid = B*V/256
__global__ __launch_bounds__(256) void k_zero_t0(const int* flag, void* out){
  int idx = blockIdx.x*256 + threadIdx.x;
  int b = idx / VV, v = idx - b*VV;
  size_t o = (size_t)b*TT*VV + v;
  if(*flag) ((u16*)out)[o] = 0;
  else      ((float*)out)[o] = 0.f;
}

// ---------------------------------------------------------------------------
// Batched fc GEMM: C[m,n] = A[m,:] . W[n,:] + b[n]; m = t*32+b -> out[b,t+1,n]
template<bool BF>
__device__ void fc_body(const u16* A, const void* W, const void* bias, void* out)
{
  __shared__ u16 As[128*72];   // +8 bf16 pad per row
  __shared__ u16 Bs[128*72];
  int bm = blockIdx.x, bn = blockIdx.y;
  int tid = threadIdx.x;
  int wave = tid>>6, lane = tid&63;
  int wr = wave>>1, wc = wave&1;
  f32x4 acc[4][4];
  f32x4 zero = {0.f,0.f,0.f,0.f};
  #pragma unroll
  for(int i=0;i<4;i++)
    #pragma unroll
    for(int j=0;j<4;j++) acc[i][j]=zero;

  int row = tid>>1, half = tid&1;
  const size_t gA = (size_t)(bm*128 + row)*512 + half*32;
  const size_t gB = (size_t)(bn*128 + row)*512 + half*32;
  u16* lA = As + row*72 + half*32;
  u16* lB = Bs + row*72 + half*32;

  for(int kk=0;kk<8;kk++){
    int k0 = kk*64;
    if(kk) __syncthreads();
    stage32<true>(A, gA + k0, lA);
    stage32<BF>(W, gB + k0, lB);
    __syncthreads();
    #pragma unroll
    for(int ks=0;ks<2;ks++){
      int kof = ks*32 + (lane>>4)*8;
      bf16x8 af[4], bfv[4];
      #pragma unroll
      for(int i=0;i<4;i++){
        af[i]  = *(const bf16x8*)(As + (wr*64 + i*16 + (lane&15))*72 + kof);
        bfv[i] = *(const bf16x8*)(Bs + (wc*64 + i*16 + (lane&15))*72 + kof);
      }
      #pragma unroll
      for(int i=0;i<4;i++)
        #pragma unroll
        for(int j=0;j<4;j++)
          acc[i][j] = __builtin_amdgcn_mfma_f32_16x16x32_bf16(af[i], bfv[j], acc[i][j], 0, 0, 0);
    }
  }
  // epilogue: C/D layout col = lane&15, row = (lane>>4)*4 + r   [m89-verified]
  int quad = lane>>4, col = lane&15;
  #pragma unroll
  for(int j=0;j<4;j++){
    int n = bn*128 + wc*64 + j*16 + col;
    float bsv = wld<BF>(bias, n);
    #pragma unroll
    for(int i=0;i<4;i++){
      int mbase = bm*128 + wr*64 + i*16 + quad*4;
      #pragma unroll
      for(int r=0;r<4;r++){
        int m = mbase + r;
        if(m < TD*BB){
          int t = m >> 5, b = m & 31;
          size_t o = ((size_t)(b*TT + t + 1))*VV + n;
          float v = acc[i][j][r] + bsv;
          if constexpr (BF) ((u16*)out)[o] = f2bf(v);
          else              ((float*)out)[o] = v;
        }
      }
    }
  }
}
__global__ __launch_bounds__(256) void k_fc(
  const int* flag, const u16* A, const void* W, const void* bias, void* out)
{
  if(*flag) fc_body<true>(A, W, bias, out);
  else      fc_body<false>(A, W, bias, out);
}

// ---------------------------------------------------------------------------
extern "C" void kernel_launch(void* const* d_in, const int* in_sizes, int n_in,
                              void* d_out, int out_size, void* d_ws, size_t ws_size,
                              hipStream_t stream)
{
  const int* src = (const int*)d_in[0];
  const int* trg = (const int*)d_in[1];
  const void* src_emb = d_in[2];
  const void* trg_emb = d_in[3];
  const void* eWih = d_in[4];
  const void* eWhh = d_in[5];
  const void* ebih = d_in[6];
  const void* ebhh = d_in[7];
  const void* d0Wih = d_in[8];
  const void* d0Whh = d_in[9];
  const void* d0bih = d_in[10];
  const void* d0bhh = d_in[11];
  const void* d1Wih = d_in[12];
  const void* d1Whh = d_in[13];
  const void* d1bih = d_in[14];
  const void* d1bhh = d_in[15];
  const void* aW  = d_in[16];
  const void* ab  = d_in[17];
  const void* vW  = d_in[18];
  const void* vb  = d_in[19];
  const void* fcW = d_in[20];
  const void* fcb = d_in[21];

  char* w = (char*)d_ws;
  int*   flag    = (int*)w;   w += 16;
  float* enc_gi  = (float*)w; w += (size_t)SS*BB*H3*4;   // 25.2 MB
  float* trg_gi  = (float*)w; w += (size_t)TD*BB*H3*4;   // 12.4 MB
  float* enc_outs= (float*)w; w += (size_t)BB*SS*HH*4;   // 8.4 MB
  float* P       = (float*)w; w += (size_t)BB*SS*HH*4;   // 8.4 MB
  float* hE      = (float*)w; w += (size_t)2*BB*HH*4;
  float* h0b     = (float*)w; w += (size_t)2*BB*HH*4;
  float* h1b     = (float*)w; w += (size_t)2*BB*HH*4;
  float* Abuf    = (float*)w; w += (size_t)BB*HH*4;
  float* Cpart   = (float*)w; w += (size_t)BB*8*HH*4;
  float* Ssum    = (float*)w; w += (size_t)BB*8*4;
  u16*   h1_all  = (u16*)w;   w += (size_t)MFC*HH*2;
  unsigned int* bctr = (unsigned int*)w; w += (size_t)BB*64*4;

  // init (ws is poisoned 0xAA before every call)
  (void)hipMemsetAsync(hE, 0, BB*HH*4, stream);                        // encoder h0 = 0
  (void)hipMemsetAsync(h1_all + (size_t)TD*BB*HH, 0, 32*HH*2, stream); // fc pad rows
  (void)hipMemsetAsync(bctr, 0, (size_t)BB*64*4, stream);              // barrier counters

  // dtype detection (writes flag)
  k_detect<<<1,64,0,stream>>>(fcW, flag);

  // batched input-gate projections (parallel work, single launches)
  k_emb_gi<<<SS*BB*6, 256, 0, stream>>>(flag, src, SS, src_emb, eWih, EE, ebih, enc_gi);
  k_emb_gi<<<TD*BB*6, 256, 0, stream>>>(flag, trg, TT, trg_emb, d0Wih, EHD, d0bih, trg_gi);

  // fused persistent encoder + attn-proj + decoder (cooperative for
  // guaranteed co-residency of all 256 blocks; no grid.sync used)
  EncDecParams prm;
  prm.flag = flag;
  prm.eWhh = eWhh; prm.ebhh = ebhh;
  prm.enc_gi = enc_gi;
  prm.enc_outs = enc_outs;
  prm.aW = aW; prm.ab = ab; prm.vW = vW; prm.vb = vb;
  prm.d0Wih = d0Wih; prm.d0Whh = d0Whh; prm.d0bhh = d0bhh;
  prm.trg_gi = trg_gi;
  prm.d1Wih = d1Wih; prm.d1bih = d1bih; prm.d1Whh = d1Whh; prm.d1bhh = d1bhh;
  prm.hE = hE; prm.h0b = h0b; prm.h1b = h1b;
  prm.P = P; prm.Abuf = Abuf; prm.Cpart = Cpart; prm.Ssum = Ssum;
  prm.h1_all = h1_all;
  prm.bctr = bctr;

  void* kargs[] = { (void*)&prm };
  (void)hipLaunchCooperativeKernel(reinterpret_cast<void*>(&k_encdec),
                                   dim3(256), dim3(256), kargs, 0, stream);

  // outputs
  k_zero_t0<<<(BB*VV)/256, 256, 0, stream>>>(flag, d_out);
  dim3 g(16, 250);
  k_fc<<<g, 256, 0, stream>>>(flag, h1_all, fcW, fcb, d_out);
}

// Round 4
// 8201.650 us; speedup vs baseline: 2.1467x; 1.0265x over previous
//
#include <hip/hip_runtime.h>
#include <hip/hip_bf16.h>

// Problem dims
#define BB 32
#define SS 128
#define TT 64
#define EE 64
#define HH 512
#define H3 1536
#define VV 32000
#define EHD 576      // E + H (dec0 input width)
#define TD 63        // decoder steps
#define MFC 2048     // padded M for fc GEMM (63*32 = 2016 real rows)

typedef unsigned short u16;
typedef unsigned int   u32;

typedef __attribute__((ext_vector_type(8))) short bf16x8;
typedef __attribute__((ext_vector_type(4))) float f32x4;

__device__ __forceinline__ float bf2f(u16 u){ return __uint_as_float(((u32)u)<<16); }
__device__ __forceinline__ u16 f2bf(float f){
  u32 u = __float_as_uint(f);
  u += 0x7FFFu + ((u>>16)&1u);       // RNE
  return (u16)(u>>16);
}
__device__ __forceinline__ float sigm(float x){ return 1.f/(1.f+__expf(-x)); }
__device__ __forceinline__ float tanh_f(float x){ return 1.f - 2.f/(1.f+__expf(2.f*x)); }

__device__ __forceinline__ void bf8f(uint4 q, float* f){
  f[0]=__uint_as_float(q.x<<16); f[1]=__uint_as_float(q.x&0xFFFF0000u);
  f[2]=__uint_as_float(q.y<<16); f[3]=__uint_as_float(q.y&0xFFFF0000u);
  f[4]=__uint_as_float(q.z<<16); f[5]=__uint_as_float(q.z&0xFFFF0000u);
  f[6]=__uint_as_float(q.w<<16); f[7]=__uint_as_float(q.w&0xFFFF0000u);
}

// ---- dtype-abstracted weight access: BF=true -> bf16 data, BF=false -> fp32 data
template<bool BF>
__device__ __forceinline__ void wload8(const void* base, size_t eoff, float* f){
  if constexpr (BF){
    uint4 q = *(const uint4*)((const u16*)base + eoff);
    bf8f(q, f);
  } else {
    const float4* p = (const float4*)((const float*)base + eoff);
    float4 a = p[0], b = p[1];
    f[0]=a.x; f[1]=a.y; f[2]=a.z; f[3]=a.w;
    f[4]=b.x; f[5]=b.y; f[6]=b.z; f[7]=b.w;
  }
}
template<bool BF>
__device__ __forceinline__ float wld(const void* base, size_t eoff){
  if constexpr (BF) return bf2f(((const u16*)base)[eoff]);
  else              return ((const float*)base)[eoff];
}
// stage 32 weight elements -> LDS as bf16
template<bool BF>
__device__ __forceinline__ void stage32(const void* gbase, size_t eoff, u16* lds){
  if constexpr (BF){
    const uint4* g = (const uint4*)((const u16*)gbase + eoff);
    uint4* l = (uint4*)lds;
    l[0]=g[0]; l[1]=g[1]; l[2]=g[2]; l[3]=g[3];
  } else {
    const float4* g = (const float4*)((const float*)gbase + eoff);
    #pragma unroll
    for(int i=0;i<8;i++){
      float4 v = g[i];
      u16* d = lds + i*4;
      d[0]=f2bf(v.x); d[1]=f2bf(v.y); d[2]=f2bf(v.z); d[3]=f2bf(v.w);
    }
  }
}

// ---------------------------------------------------------------------------
// Coherent 8B load (per-access device coherence; does NOT invalidate caches).
__device__ __forceinline__ float2 cld2(const float* p){
  unsigned long long u = __hip_atomic_load((const unsigned long long*)p,
                                           __ATOMIC_RELAXED, __HIP_MEMORY_SCOPE_AGENT);
  float2 r;
  r.x = __uint_as_float((u32)u);
  r.y = __uint_as_float((u32)(u>>32));
  return r;
}
__device__ __forceinline__ float cld1(const float* p){
  u32 u = __hip_atomic_load((const u32*)p, __ATOMIC_RELAXED, __HIP_MEMORY_SCOPE_AGENT);
  return __uint_as_float(u);
}

// ---------------------------------------------------------------------------
// Per-batch 8-block barrier. Arrival = release-add (writes back this XCD's few
// dirty lines so remote readers see them). Spin = relaxed agent load. The
// acquire is WORKGROUP scope only (ordering, no L2 invalidate) — remote data
// is read with per-access coherent loads (cld2), so no blanket invalidate is
// needed and weights stay L2-resident.
__device__ __forceinline__ void bbar(unsigned int* ctr, int tid, unsigned int target){
  __syncthreads();
  if(tid==0){
    __hip_atomic_fetch_add(ctr, 1u, __ATOMIC_RELEASE, __HIP_MEMORY_SCOPE_AGENT);
    while(__hip_atomic_load(ctr, __ATOMIC_RELAXED, __HIP_MEMORY_SCOPE_AGENT) < target){
      __builtin_amdgcn_s_sleep(1);
    }
    __builtin_amdgcn_fence(__ATOMIC_ACQUIRE, "workgroup");
  }
  __syncthreads();
}

// ---------------------------------------------------------------------------
// dtype detector
__global__ __launch_bounds__(64) void k_detect(const void* w, int* flag){
  int tid = threadIdx.x;
  const u16* p = (const u16*)w;
  float m = 0.f;
  #pragma unroll
  for(int i=0;i<16;i++){
    float v = fabsf(bf2f(p[tid*16+i]));
    m = fmaxf(m, v);
  }
  #pragma unroll
  for(int off=32;off;off>>=1) m = fmaxf(m, __shfl_down(m, off));
  if(tid==0) *flag = (m < 16.f) ? 1 : 0;
}

// ---------------------------------------------------------------------------
// Batched embedding -> input-gate projection
template<bool BF>
__device__ void emb_gi_body(const int* toks, int tstride, const void* emb_tab,
                            const void* W_ih, int wstride, const void* b_ih,
                            float* gi)
{
  int blk = blockIdx.x;
  int jc = blk % 6; int b = (blk/6) % BB; int t = blk/(6*BB);
  int tid = threadIdx.x;
  int tok = toks[b*tstride + t];
  __shared__ float emb[EE];
  if(tid < EE) emb[tid] = wld<BF>(emb_tab, (size_t)tok*EE + tid);
  __syncthreads();
  int j = jc*256 + tid;
  float acc = wld<BF>(b_ih, j);
  size_t roff = (size_t)j*wstride;
  #pragma unroll
  for(int i=0;i<8;i++){
    float f[8]; wload8<BF>(W_ih, roff + i*8, f);
    #pragma unroll
    for(int l=0;l<8;l++) acc += emb[i*8+l]*f[l];
  }
  gi[((size_t)t*BB + b)*H3 + j] = acc;
}
__global__ __launch_bounds__(256) void k_emb_gi(
    const int* flag, const int* toks, int tstride, const void* emb_tab,
    const void* W_ih, int wstride, const void* b_ih, float* gi)
{
  if(*flag) emb_gi_body<true>(toks,tstride,emb_tab,W_ih,wstride,b_ih,gi);
  else      emb_gi_body<false>(toks,tstride,emb_tab,W_ih,wstride,b_ih,gi);
}

// ---------------------------------------------------------------------------
// Unified shared memory for the fused persistent kernel.
// a/b are skewed: element k lives at index k + (k>>7)*8, so the four t4
// k-blocks (stride 128) land on banks offset by 8 -> no 4-way conflicts.
struct SMem {
  union {
    struct {
      float a[544];         // ctx / xs / As (As unskewed)
      float b[544];         // hs / hsr / vs (vs unskewed)
      float red[6][256];
      float eS[16];
    };
    float es16[16][520];    // attn_proj staging: 16 enc rows (+8 pad)
  };
};

struct EncDecParams {
  const int* flag;
  const void *eWhh, *ebhh;
  const float* enc_gi;
  float* enc_outs;
  const void *aW, *ab, *vW, *vb;
  const void *d0Wih, *d0Whh, *d0bhh;
  const float* trg_gi;
  const void *d1Wih, *d1bih, *d1Whh, *d1bhh;
  float* hE;       // [2][B][H]
  float* h0b;      // [2][B][H]
  float* h1b;      // [2][B][H]
  float* P;        // [B][S][H]
  float* Abuf;     // [B][H]
  float* Cpart;    // [B][8][H]
  float* Ssum;     // [B][8]
  u16* h1_all;     // [MFC][H]
  unsigned int* bctr;  // [B] barrier counters, 64-int stride
};

// ---- encoder GRU step: block (b,q), thread (jj = tid>>2, t4 = tid&3) ----
template<bool BF>
__device__ void enc_step_dev(SMem& sm, int b, int q, int tid,
                             const float* hin, float* hout,
                             const void* W_hh, const void* b_hh,
                             const float* gi_t, float* enc_outs, int t,
                             float* h0init, float* h1init)
{
  float* hs = sm.b;
  {
    float2 h2 = cld2(hin + b*HH + 2*tid);
    int sk = ((2*tid)>>7)<<3;
    hs[2*tid+sk] = h2.x; hs[2*tid+1+sk] = h2.y;
  }
  __syncthreads();
  int jj = tid >> 2, t4 = tid & 3;
  int j = q*64 + jj;
  int k0 = t4*128;
  const float* hsb = hs + t4*136;      // skewed base for this k-slice
  float ar=0.f, az=0.f, an=0.f;
  size_t orr = (size_t)j*HH + k0;
  size_t oz = (size_t)(512+j)*HH + k0;
  size_t on = (size_t)(1024+j)*HH + k0;
  #pragma unroll 4
  for(int i=0;i<16;i++){
    float f[8];
    wload8<BF>(W_hh, orr + i*8, f);
    #pragma unroll
    for(int l=0;l<8;l++) ar += hsb[i*8+l]*f[l];
    wload8<BF>(W_hh, oz + i*8, f);
    #pragma unroll
    for(int l=0;l<8;l++) az += hsb[i*8+l]*f[l];
    wload8<BF>(W_hh, on + i*8, f);
    #pragma unroll
    for(int l=0;l<8;l++) an += hsb[i*8+l]*f[l];
  }
  sm.red[0][tid]=ar; sm.red[1][tid]=az; sm.red[2][tid]=an;
  __syncthreads();
  if(t4==0){
    float gr = sm.red[0][tid]+sm.red[0][tid+1]+sm.red[0][tid+2]+sm.red[0][tid+3] + wld<BF>(b_hh, j);
    float gz = sm.red[1][tid]+sm.red[1][tid+1]+sm.red[1][tid+2]+sm.red[1][tid+3] + wld<BF>(b_hh, 512+j);
    float gn = sm.red[2][tid]+sm.red[2][tid+1]+sm.red[2][tid+2]+sm.red[2][tid+3] + wld<BF>(b_hh, 1024+j);
    const float* gib = gi_t + b*H3;
    float r = sigm(gib[j] + gr);
    float z = sigm(gib[512+j] + gz);
    float n = tanh_f(gib[1024+j] + r*gn);
    int jsk = j + ((j>>7)<<3);
    float hn = (1.f - z)*n + z*hs[jsk];
    hout[b*HH + j] = hn;
    enc_outs[((size_t)b*SS + t)*HH + j] = hn;
    if(h0init){ h0init[b*HH+j] = hn; h1init[b*HH+j] = hn; }
  }
}

// ---- attention enc-projection for this block's 16 s-rows of batch b ----
template<bool BF>
__device__ void attn_proj_blk(SMem& sm, int b, int q, int tid,
                              const float* enc_outs, const void* attn_W,
                              const void* attn_b, float* P)
{
  #pragma unroll 4
  for(int i=0;i<16;i++){
    const float* er = enc_outs + ((size_t)b*SS + q*16 + i)*HH;
    float2 v = cld2(er + 2*tid);       // cross-block rows -> coherent read
    sm.es16[i][2*tid]   = v.x;
    sm.es16[i][2*tid+1] = v.y;
  }
  __syncthreads();
  #pragma unroll
  for(int rr=0; rr<2; rr++){
    int j = rr*256 + tid;
    float bj = wld<BF>(attn_b, j);
    float acc[16];
    #pragma unroll
    for(int i=0;i<16;i++) acc[i] = bj;
    size_t roff = (size_t)j*1024 + 512;
    for(int kk=0;kk<64;kk++){
      float f[8]; wload8<BF>(attn_W, roff + kk*8, f);
      #pragma unroll
      for(int i=0;i<16;i++){
        const float4* e4 = (const float4*)(&sm.es16[i][kk*8]);
        float4 ea = e4[0], eb = e4[1];
        acc[i] += ea.x*f[0]+ea.y*f[1]+ea.z*f[2]+ea.w*f[3]
                + eb.x*f[4]+eb.y*f[5]+eb.z*f[6]+eb.w*f[7];
      }
    }
    #pragma unroll
    for(int i=0;i<16;i++)
      P[((size_t)b*SS + q*16 + i)*HH + j] = acc[i];
  }
  __syncthreads();
}

// ---- A[b,j] = attn_W[j,0:512] . h1[b,:], block (b,q), k-split by t4 ----
template<bool BF>
__device__ void dec_A_dev(SMem& sm, int b, int q, int tid,
                          const float* h1, const void* attn_W, float* Abuf)
{
  float* hsr = sm.b;
  {
    float2 h2 = cld2(h1 + b*HH + 2*tid);
    int sk = ((2*tid)>>7)<<3;
    hsr[2*tid+sk] = h2.x; hsr[2*tid+1+sk] = h2.y;
  }
  __syncthreads();
  int jj = tid>>2, t4 = tid&3, j = q*64+jj, k0 = t4*128;
  const float* hsrb = hsr + t4*136;
  size_t roff = (size_t)j*1024 + k0;
  float acc = 0.f;
  #pragma unroll 4
  for(int i=0;i<16;i++){
    float f[8]; wload8<BF>(attn_W, roff + i*8, f);
    #pragma unroll
    for(int l=0;l<8;l++) acc += hsrb[i*8+l]*f[l];
  }
  sm.red[0][tid]=acc;
  __syncthreads();
  if(t4==0){
    Abuf[b*HH + j] = sm.red[0][tid]+sm.red[0][tid+1]+sm.red[0][tid+2]+sm.red[0][tid+3];
  }
}

// ---- scores + exp + partial softmax-weighted context, block (b, sb=q) ----
template<bool BF>
__device__ void dec_scores_dev(SMem& sm, int b, int sb, int tid,
                               const float* Abuf, const float* P,
                               const float* enc_outs, const void* vW,
                               const void* vb, float* Cpart, float* Ssum)
{
  float* As = sm.a;   // unskewed in this phase (lane-consecutive reads)
  float* vs = sm.b;
  {
    float2 a2 = cld2(Abuf + b*HH + 2*tid);   // written by other blocks
    As[2*tid]=a2.x; As[2*tid+1]=a2.y;
  }
  vs[tid]=wld<BF>(vW, tid); vs[tid+256]=wld<BF>(vW, tid+256);
  __syncthreads();
  int wave = tid>>6, lane = tid&63;
  float vbf = wld<BF>(vb, 0);
  #pragma unroll
  for(int i=0;i<4;i++){
    int s = sb*16 + wave*4 + i;
    const float* Prow = P + ((size_t)b*SS+s)*HH;   // own block's rows
    float part = 0.f;
    #pragma unroll
    for(int kk=0;kk<8;kk++){
      int k = lane + kk*64;
      part += vs[k]*tanh_f(As[k]+Prow[k]);
    }
    #pragma unroll
    for(int off=32;off;off>>=1) part += __shfl_down(part, off);
    if(lane==0) sm.eS[wave*4+i] = __expf(part + vbf);
  }
  __syncthreads();
  {
    float c0=0.f, c1=0.f;
    const float* eb0 = enc_outs + ((size_t)b*SS + sb*16)*HH + 2*tid;
    #pragma unroll
    for(int i=0;i<16;i++){
      float2 v = cld2(eb0 + (size_t)i*HH);   // rows j-sliced by other blocks
      c0 += sm.eS[i]*v.x; c1 += sm.eS[i]*v.y;
    }
    float* cp = Cpart + ((size_t)b*8+sb)*HH;
    cp[2*tid]=c0; cp[2*tid+1]=c1;
  }
  if(tid==0){ float ss=0.f; for(int i=0;i<16;i++) ss+=sm.eS[i]; Ssum[b*8+sb]=ss; }
}

// ---- decoder GRU layer 0, block (b,q) ----
template<bool BF>
__device__ void dec_h0_dev(SMem& sm, int b, int q, int tid,
                           const float* h0in, float* h0out,
                           const float* Cpart, const float* Ssum,
                           const void* W_ih, const void* W_hh,
                           const void* b_hh, const float* gi_t)
{
  float* ctx = sm.a;
  float* hs  = sm.b;
  float ssum = 0.f;
  #pragma unroll
  for(int sb=0;sb<8;sb++) ssum += cld1(&Ssum[b*8+sb]);
  float invS = 1.f/ssum;
  {
    float c0=0.f, c1=0.f;
    #pragma unroll
    for(int sb=0;sb<8;sb++){
      float2 v = cld2(Cpart + ((size_t)b*8+sb)*HH + 2*tid);
      c0+=v.x; c1+=v.y;
    }
    int sk = ((2*tid)>>7)<<3;
    ctx[2*tid+sk]=c0*invS; ctx[2*tid+1+sk]=c1*invS;
    float2 h2 = cld2(h0in + b*HH + 2*tid);
    hs[2*tid+sk]=h2.x; hs[2*tid+1+sk]=h2.y;
  }
  __syncthreads();
  int jj = tid>>2, t4 = tid&3, j = q*64+jj, k0 = t4*128;
  const float* ctxb = ctx + t4*136;
  const float* hsb  = hs  + t4*136;
  float pr=0.f,pz=0.f,pn=0.f,qr=0.f,qz=0.f,qn=0.f;
  size_t oir = (size_t)j*EHD + 64 + k0;
  size_t oiz = (size_t)(512+j)*EHD + 64 + k0;
  size_t oin = (size_t)(1024+j)*EHD + 64 + k0;
  size_t ohr = (size_t)j*HH + k0;
  size_t ohz = (size_t)(512+j)*HH + k0;
  size_t ohn = (size_t)(1024+j)*HH + k0;
  #pragma unroll 2
  for(int i=0;i<16;i++){
    float f[8];
    wload8<BF>(W_ih, oir + i*8, f);
    #pragma unroll
    for(int l=0;l<8;l++) pr += ctxb[i*8+l]*f[l];
    wload8<BF>(W_ih, oiz + i*8, f);
    #pragma unroll
    for(int l=0;l<8;l++) pz += ctxb[i*8+l]*f[l];
    wload8<BF>(W_ih, oin + i*8, f);
    #pragma unroll
    for(int l=0;l<8;l++) pn += ctxb[i*8+l]*f[l];
    wload8<BF>(W_hh, ohr + i*8, f);
    #pragma unroll
    for(int l=0;l<8;l++) qr += hsb[i*8+l]*f[l];
    wload8<BF>(W_hh, ohz + i*8, f);
    #pragma unroll
    for(int l=0;l<8;l++) qz += hsb[i*8+l]*f[l];
    wload8<BF>(W_hh, ohn + i*8, f);
    #pragma unroll
    for(int l=0;l<8;l++) qn += hsb[i*8+l]*f[l];
  }
  sm.red[0][tid]=pr; sm.red[1][tid]=pz; sm.red[2][tid]=pn;
  sm.red[3][tid]=qr; sm.red[4][tid]=qz; sm.red[5][tid]=qn;
  __syncthreads();
  if(t4==0){
    float gir = gi_t[b*H3 + j]        + sm.red[0][tid]+sm.red[0][tid+1]+sm.red[0][tid+2]+sm.red[0][tid+3];
    float giz = gi_t[b*H3 + 512 + j]  + sm.red[1][tid]+sm.red[1][tid+1]+sm.red[1][tid+2]+sm.red[1][tid+3];
    float gin = gi_t[b*H3 + 1024 + j] + sm.red[2][tid]+sm.red[2][tid+1]+sm.red[2][tid+2]+sm.red[2][tid+3];
    float ghr = sm.red[3][tid]+sm.red[3][tid+1]+sm.red[3][tid+2]+sm.red[3][tid+3] + wld<BF>(b_hh, j);
    float ghz = sm.red[4][tid]+sm.red[4][tid+1]+sm.red[4][tid+2]+sm.red[4][tid+3] + wld<BF>(b_hh, 512+j);
    float ghn = sm.red[5][tid]+sm.red[5][tid+1]+sm.red[5][tid+2]+sm.red[5][tid+3] + wld<BF>(b_hh, 1024+j);
    float r = sigm(gir+ghr), z = sigm(giz+ghz), n = tanh_f(gin + r*ghn);
    int jsk = j + ((j>>7)<<3);
    h0out[b*HH + j] = (1.f - z)*n + z*hs[jsk];
  }
}

// ---- decoder GRU layer 1 (+ bf16 h1 row for fc GEMM), block (b,q) ----
template<bool BF>
__device__ void dec_h1_dev(SMem& sm, int b, int q, int tid,
                           const float* xin, const float* h1in, float* h1out,
                           const void* W_ih, const void* b_ih,
                           const void* W_hh, const void* b_hh,
                           u16* h1_all_t)
{
  float* xs = sm.a;
  float* hs = sm.b;
  {
    int sk = ((2*tid)>>7)<<3;
    float2 x2 = cld2(xin + b*HH + 2*tid);
    xs[2*tid+sk]=x2.x; xs[2*tid+1+sk]=x2.y;
    float2 h2 = cld2(h1in + b*HH + 2*tid);
    hs[2*tid+sk]=h2.x; hs[2*tid+1+sk]=h2.y;
  }
  __syncthreads();
  int jj = tid>>2, t4 = tid&3, j = q*64+jj, k0 = t4*128;
  const float* xsb = xs + t4*136;
  const float* hsb = hs + t4*136;
  float pr=0.f,pz=0.f,pn=0.f,qr=0.f,qz=0.f,qn=0.f;
  size_t oir = (size_t)j*HH + k0;
  size_t oiz = (size_t)(512+j)*HH + k0;
  size_t oin = (size_t)(1024+j)*HH + k0;
  #pragma unroll 2
  for(int i=0;i<16;i++){
    float f[8];
    wload8<BF>(W_ih, oir + i*8, f);
    #pragma unroll
    for(int l=0;l<8;l++) pr += xsb[i*8+l]*f[l];
    wload8<BF>(W_ih, oiz + i*8, f);
    #pragma unroll
    for(int l=0;l<8;l++) pz += xsb[i*8+l]*f[l];
    wload8<BF>(W_ih, oin + i*8, f);
    #pragma unroll
    for(int l=0;l<8;l++) pn += xsb[i*8+l]*f[l];
    wload8<BF>(W_hh, oir + i*8, f);
    #pragma unroll
    for(int l=0;l<8;l++) qr += hsb[i*8+l]*f[l];
    wload8<BF>(W_hh, oiz + i*8, f);
    #pragma unroll
    for(int l=0;l<8;l++) qz += hsb[i*8+l]*f[l];
    wload8<BF>(W_hh, oin + i*8, f);
    #pragma unroll
    for(int l=0;l<8;l++) qn += hsb[i*8+l]*f[l];
  }
  sm.red[0][tid]=pr; sm.red[1][tid]=pz; sm.red[2][tid]=pn;
  sm.red[3][tid]=qr; sm.red[4][tid]=qz; sm.red[5][tid]=qn;
  __syncthreads();
  if(t4==0){
    float gir = wld<BF>(b_ih, j)      + sm.red[0][tid]+sm.red[0][tid+1]+sm.red[0][tid+2]+sm.red[0][tid+3];
    float giz = wld<BF>(b_ih, 512+j)  + sm.red[1][tid]+sm.red[1][tid+1]+sm.red[1][tid+2]+sm.red[1][tid+3];
    float gin = wld<BF>(b_ih, 1024+j) + sm.red[2][tid]+sm.red[2][tid+1]+sm.red[2][tid+2]+sm.red[2][tid+3];
    float ghr = sm.red[3][tid]+sm.red[3][tid+1]+sm.red[3][tid+2]+sm.red[3][tid+3] + wld<BF>(b_hh, j);
    float ghz = sm.red[4][tid]+sm.red[4][tid+1]+sm.red[4][tid+2]+sm.red[4][tid+3] + wld<BF>(b_hh, 512+j);
    float ghn = sm.red[5][tid]+sm.red[5][tid+1]+sm.red[5][tid+2]+sm.red[5][tid+3] + wld<BF>(b_hh, 1024+j);
    float r = sigm(gir+ghr), z = sigm(giz+ghz), n = tanh_f(gin + r*ghn);
    int jsk = j + ((j>>7)<<3);
    float hn = (1.f - z)*n + z*hs[jsk];
    h1out[b*HH + j] = hn;
    h1_all_t[b*HH + j] = f2bf(hn);
  }
}

// ---------------------------------------------------------------------------
// Fused persistent encoder + attn-proj + decoder. 256 blocks x 256 threads.
// Mapping b = blk>>3, q = blk&7: blk%8 == q, so (assuming round-robin XCD
// dispatch) slice q of every weight matrix is only read by blocks on XCD q
// -> per-XCD weight footprint ~1.4 MB, L2-resident across all steps.
template<bool BF>
__device__ void encdec_body(const EncDecParams& p, SMem& sm)
{
  int blk = blockIdx.x, tid = threadIdx.x;
  int b = blk >> 3, q = blk & 7;
  unsigned int* ctr = p.bctr + b*64;     // one cacheline per batch
  unsigned int bt = 0;

  // ---- encoder: 128 steps, per-batch barrier each ----
  for(int t=0;t<SS;t++){
    enc_step_dev<BF>(sm, b, q, tid,
        p.hE + (t&1)*BB*HH, p.hE + ((t+1)&1)*BB*HH,
        p.eWhh, p.ebhh, p.enc_gi + (size_t)t*BB*H3, p.enc_outs, t,
        (t==SS-1)? p.h0b : (float*)nullptr,
        (t==SS-1)? p.h1b : (float*)nullptr);
    bt += 8; bbar(ctr, tid, bt);
  }

  // ---- step-invariant attention enc-projection (this block's 16 s-rows) ----
  attn_proj_blk<BF>(sm, b, q, tid, p.enc_outs, p.aW, p.ab, p.P);
  bt += 8; bbar(ctr, tid, bt);

  // ---- decoder: 63 steps x 4 phases, per-batch barriers ----
  for(int t=0;t<TD;t++){
    int pi = t&1, po = (t+1)&1;
    dec_A_dev<BF>(sm, b, q, tid, p.h1b + pi*BB*HH, p.aW, p.Abuf);
    bt += 8; bbar(ctr, tid, bt);
    dec_scores_dev<BF>(sm, b, q, tid, p.Abuf, p.P, p.enc_outs, p.vW, p.vb,
                       p.Cpart, p.Ssum);
    bt += 8; bbar(ctr, tid, bt);
    dec_h0_dev<BF>(sm, b, q, tid, p.h0b + pi*BB*HH, p.h0b + po*BB*HH,
                   p.Cpart, p.Ssum, p.d0Wih, p.d0Whh, p.d0bhh,
                   p.trg_gi + (size_t)t*BB*H3);
    bt += 8; bbar(ctr, tid, bt);
    dec_h1_dev<BF>(sm, b, q, tid, p.h0b + po*BB*HH, p.h1b + pi*BB*HH,
                   p.h1b + po*BB*HH, p.d1Wih, p.d1bih, p.d1Whh, p.d1bhh,
                   p.h1_all + (size_t)t*BB*HH);
    bt += 8; bbar(ctr, tid, bt);
  }
}

__global__ __launch_bounds__(256) void k_encdec(EncDecParams p)
{
  __shared__ SMem sm;
  if(*p.flag) encdec_body<true>(p, sm);
  else        encdec_body<false>(p, sm);
}

// ---------------------------------------------------------------------------
// out[:, 0, :] = 0.   grid = B*V/256
__global__ __launch_bounds__(256) void k_zero_t0(const int* flag, void* out){
  int idx = blockIdx.x*256 + threadIdx.x;
  int b = idx / VV, v = idx - b*VV;
  size_t o = (size_t)b*TT*VV + v;
  if(*flag) ((u16*)out)[o] = 0;
  else      ((float*)out)[o] = 0.f;
}

// ---------------------------------------------------------------------------
// Batched fc GEMM: C[m,n] = A[m,:] . W[n,:] + b[n]; m = t*32+b -> out[b,t+1,n]
template<bool BF>
__device__ void fc_body(const u16* A, const void* W, const void* bias, void* out)
{
  __shared__ u16 As[128*72];   // +8 bf16 pad per row
  __shared__ u16 Bs[128*72];
  int bm = blockIdx.x, bn = blockIdx.y;
  int tid = threadIdx.x;
  int wave = tid>>6, lane = tid&63;
  int wr = wave>>1, wc = wave&1;
  f32x4 acc[4][4];
  f32x4 zero = {0.f,0.f,0.f,0.f};
  #pragma unroll
  for(int i=0;i<4;i++)
    #pragma unroll
    for(int j=0;j<4;j++) acc[i][j]=zero;

  int row = tid>>1, half = tid&1;
  const size_t gA = (size_t)(bm*128 + row)*512 + half*32;
  const size_t gB = (size_t)(bn*128 + row)*512 + half*32;
  u16* lA = As + row*72 + half*32;
  u16* lB = Bs + row*72 + half*32;

  for(int kk=0;kk<8;kk++){
    int k0 = kk*64;
    if(kk) __syncthreads();
    stage32<true>(A, gA + k0, lA);
    stage32<BF>(W, gB + k0, lB);
    __syncthreads();
    #pragma unroll
    for(int ks=0;ks<2;ks++){
      int kof = ks*32 + (lane>>4)*8;
      bf16x8 af[4], bfv[4];
      #pragma unroll
      for(int i=0;i<4;i++){
        af[i]  = *(const bf16x8*)(As + (wr*64 + i*16 + (lane&15))*72 + kof);
        bfv[i] = *(const bf16x8*)(Bs + (wc*64 + i*16 + (lane&15))*72 + kof);
      }
      #pragma unroll
      for(int i=0;i<4;i++)
        #pragma unroll
        for(int j=0;j<4;j++)
          acc[i][j] = __builtin_amdgcn_mfma_f32_16x16x32_bf16(af[i], bfv[j], acc[i][j], 0, 0, 0);
    }
  }
  // epilogue: C/D layout col = lane&15, row = (lane>>4)*4 + r   [m89-verified]
  int quad = lane>>4, col = lane&15;
  #pragma unroll
  for(int j=0;j<4;j++){
    int n = bn*128 + wc*64 + j*16 + col;
    float bsv = wld<BF>(bias, n);
    #pragma unroll
    for(int i=0;i<4;i++){
      int mbase = bm*128 + wr*64 + i*16 + quad*4;
      #pragma unroll
      for(int r=0;r<4;r++){
        int m = mbase + r;
        if(m < TD*BB){
          int t = m >> 5, b = m & 31;
          size_t o = ((size_t)(b*TT + t + 1))*VV + n;
          float v = acc[i][j][r] + bsv;
          if constexpr (BF) ((u16*)out)[o] = f2bf(v);
          else              ((float*)out)[o] = v;
        }
      }
    }
  }
}
__global__ __launch_bounds__(256) void k_fc(
  const int* flag, const u16* A, const void* W, const void* bias, void* out)
{
  if(*flag) fc_body<true>(A, W, bias, out);
  else      fc_body<false>(A, W, bias, out);
}

// ---------------------------------------------------------------------------
extern "C" void kernel_launch(void* const* d_in, const int* in_sizes, int n_in,
                              void* d_out, int out_size, void* d_ws, size_t ws_size,
                              hipStream_t stream)
{
  const int* src = (const int*)d_in[0];
  const int* trg = (const int*)d_in[1];
  const void* src_emb = d_in[2];
  const void* trg_emb = d_in[3];
  const void* eWih = d_in[4];
  const void* eWhh = d_in[5];
  const void* ebih = d_in[6];
  const void* ebhh = d_in[7];
  const void* d0Wih = d_in[8];
  const void* d0Whh = d_in[9];
  const void* d0bih = d_in[10];
  const void* d0bhh = d_in[11];
  const void* d1Wih = d_in[12];
  const void* d1Whh = d_in[13];
  const void* d1bih = d_in[14];
  const void* d1bhh = d_in[15];
  const void* aW  = d_in[16];
  const void* ab  = d_in[17];
  const void* vW  = d_in[18];
  const void* vb  = d_in[19];
  const void* fcW = d_in[20];
  const void* fcb = d_in[21];

  char* w = (char*)d_ws;
  int*   flag    = (int*)w;   w += 16;
  float* enc_gi  = (float*)w; w += (size_t)SS*BB*H3*4;   // 25.2 MB
  float* trg_gi  = (float*)w; w += (size_t)TD*BB*H3*4;   // 12.4 MB
  float* enc_outs= (float*)w; w += (size_t)BB*SS*HH*4;   // 8.4 MB
  float* P       = (float*)w; w += (size_t)BB*SS*HH*4;   // 8.4 MB
  float* hE      = (float*)w; w += (size_t)2*BB*HH*4;
  float* h0b     = (float*)w; w += (size_t)2*BB*HH*4;
  float* h1b     = (float*)w; w += (size_t)2*BB*HH*4;
  float* Abuf    = (float*)w; w += (size_t)BB*HH*4;
  float* Cpart   = (float*)w; w += (size_t)BB*8*HH*4;
  float* Ssum    = (float*)w; w += (size_t)BB*8*4;
  u16*   h1_all  = (u16*)w;   w += (size_t)MFC*HH*2;
  unsigned int* bctr = (unsigned int*)w; w += (size_t)BB*64*4;

  // init (ws is poisoned 0xAA before every call)
  (void)hipMemsetAsync(hE, 0, BB*HH*4, stream);                        // encoder h0 = 0
  (void)hipMemsetAsync(h1_all + (size_t)TD*BB*HH, 0, 32*HH*2, stream); // fc pad rows
  (void)hipMemsetAsync(bctr, 0, (size_t)BB*64*4, stream);              // barrier counters

  // dtype detection (writes flag)
  k_detect<<<1,64,0,stream>>>(fcW, flag);

  // batched input-gate projections (parallel work, single launches)
  k_emb_gi<<<SS*BB*6, 256, 0, stream>>>(flag, src, SS, src_emb, eWih, EE, ebih, enc_gi);
  k_emb_gi<<<TD*BB*6, 256, 0, stream>>>(flag, trg, TT, trg_emb, d0Wih, EHD, d0bih, trg_gi);

  // fused persistent encoder + attn-proj + decoder (cooperative for
  // guaranteed co-residency of all 256 blocks; no grid.sync used)
  EncDecParams prm;
  prm.flag = flag;
  prm.eWhh = eWhh; prm.ebhh = ebhh;
  prm.enc_gi = enc_gi;
  prm.enc_outs = enc_outs;
  prm.aW = aW; prm.ab = ab; prm.vW = vW; prm.vb = vb;
  prm.d0Wih = d0Wih; prm.d0Whh = d0Whh; prm.d0bhh = d0bhh;
  prm.trg_gi = trg_gi;
  prm.d1Wih = d1Wih; prm.d1bih = d1bih; prm.d1Whh = d1Whh; prm.d1bhh = d1bhh;
  prm.hE = hE; prm.h0b = h0b; prm.h1b = h1b;
  prm.P = P; prm.Abuf = Abuf; prm.Cpart = Cpart; prm.Ssum = Ssum;
  prm.h1_all = h1_all;
  prm.bctr = bctr;

  void* kargs[] = { (void*)&prm };
  (void)hipLaunchCooperativeKernel(reinterpret_cast<void*>(&k_encdec),
                                   dim3(256), dim3(256), kargs, 0, stream);

  // outputs
  k_zero_t0<<<(BB*VV)/256, 256, 0, stream>>>(flag, d_out);
  dim3 g(16, 250);
  k_fc<<<g, 256, 0, stream>>>(flag, h1_all, fcW, fcb, d_out);
}